// Round 16
// baseline (694.468 us; speedup 1.0000x reference)
//
#include <hip/hip_runtime.h>

#define B_ 256
#define S_ 80
#define H_ 512
#define V_ 4096
#define NSTEP 27

typedef unsigned short u16;
typedef __attribute__((ext_vector_type(8))) short short8v;
typedef __attribute__((ext_vector_type(4))) float f32x4;
typedef __attribute__((ext_vector_type(4))) unsigned short ushort4v;

#define MFMA_(a,b,c) __builtin_amdgcn_mfma_f32_16x16x32_bf16(a,b,c,0,0,0)
#define MFMA3(acc, ah, al, bh, bl) do{ acc = MFMA_(ah,bh,acc); acc = MFMA_(ah,bl,acc); acc = MFMA_(al,bh,acc);}while(0)

__device__ __forceinline__ unsigned fkey(float v){
    unsigned u = __float_as_uint(v);
    return (u & 0x80000000u) ? ~u : (u | 0x80000000u);
}
__device__ __forceinline__ u16 bf16_rne(float f){
    unsigned u = __float_as_uint(f);
    return (u16)((u + 0x7FFFu + ((u >> 16) & 1u)) >> 16);
}
__device__ __forceinline__ void split_f4(float4 v, ushort4v& hi, ushort4v& lo){
    float arr[4] = {v.x, v.y, v.z, v.w};
    ushort4v h, l;
#pragma unroll
    for (int i = 0; i < 4; ++i){
        u16 hb = bf16_rne(arr[i]);
        h[i] = hb;
        l[i] = bf16_rne(arr[i] - __uint_as_float(((unsigned)hb) << 16));
    }
    hi = h; lo = l;
}

// ---------------- small matvec (weff chain) ----------------
__global__ __launch_bounds__(64) void matvec512(const float* __restrict__ W,
                                                const float* __restrict__ v,
                                                float* __restrict__ out){
    int row = blockIdx.x, lane = threadIdx.x;
    const float* wr = W + row * 512;
    float s = 0.f;
#pragma unroll
    for (int i = 0; i < 8; ++i) s += wr[lane + 64*i] * v[lane + 64*i];
#pragma unroll
    for (int off = 32; off; off >>= 1) s += __shfl_xor(s, off);
    if (lane == 0) out[row] = s;
}

// ---------------- one-time transforms (+ t1 = W4@Ww stage) ----------------
__global__ __launch_bounds__(256) void prep_all(
    const float* __restrict__ Whh, const float* __restrict__ Wo,
    const float* __restrict__ emb, const float* __restrict__ Wih,
    const float* __restrict__ elhs,
    const float* __restrict__ W4, const float* __restrict__ Ww,
    u16* __restrict__ WhhHi, u16* __restrict__ WhhLo,
    u16* __restrict__ WoThi, u16* __restrict__ WoTlo,
    u16* __restrict__ EmbHi, u16* __restrict__ EmbLo,
    u16* __restrict__ WihLHi, u16* __restrict__ WihLLo,
    u16* __restrict__ Sh, u16* __restrict__ Sl,
    float* __restrict__ t1out,
    unsigned* __restrict__ zp, int nz)
{
    __shared__ float T[64][65];
    int b = blockIdx.x, tid = threadIdx.x;
    if (b < 768){
        int idx = (b*256 + tid)*4;
        float4 v = *(const float4*)&Whh[idx];
        ushort4v h,l; split_f4(v,h,l);
        *(ushort4v*)&WhhHi[idx]=h; *(ushort4v*)&WhhLo[idx]=l;
    } else if (b < 1280){
        int lb = b - 768;
        int k0 = (lb & 7)*64, n0 = (lb >> 3)*64;
#pragma unroll
        for (int i = 0; i < 16; ++i){
            int idx = tid + i*256;
            int kk = idx >> 6, nn = idx & 63;
            T[kk][nn] = Wo[(size_t)(k0+kk)*4096 + n0+nn];
        }
        __syncthreads();
#pragma unroll
        for (int i = 0; i < 16; ++i){
            int idx = tid + i*256;
            int nn = idx >> 6, kk = idx & 63;
            float v = T[kk][nn];
            u16 hi = bf16_rne(v);
            u16 lo = bf16_rne(v - __uint_as_float(((unsigned)hi) << 16));
            size_t o = (size_t)(n0+nn)*512 + k0+kk;
            WoThi[o] = hi; WoTlo[o] = lo;
        }
    } else if (b < 5376){
        int idx = ((b-1280)*256 + tid)*4;
        float4 v = *(const float4*)&emb[idx];
        ushort4v h,l; split_f4(v,h,l);
        *(ushort4v*)&EmbHi[idx]=h; *(ushort4v*)&EmbLo[idx]=l;
    } else if (b < 6912){
        int id = ((b-5376)*256 + tid)*4;
        int r = id >> 10, c = id & 1023;
        float4 v = *(const float4*)&Wih[(size_t)r*1536 + c];
        ushort4v h,l; split_f4(v,h,l);
        *(ushort4v*)&WihLHi[id]=h; *(ushort4v*)&WihLLo[id]=l;
    } else if (b < 7040){
        int idx = ((b-6912)*256 + tid)*4;
        float4 v = *(const float4*)&elhs[idx];
        ushort4v h,l; split_f4(v,h,l);
        *(ushort4v*)&Sh[idx]=h; *(ushort4v*)&Sl[idx]=l;
    } else if (b < 7054){
        int i = ((b-7040)*256 + tid)*4;
        if (i < nz){ zp[i]=0u; zp[i+1]=0u; zp[i+2]=0u; zp[i+3]=0u; }
    } else {
        // t1 = W4 @ Ww : 128 blocks x 4 rows (4 waves/block, 1 row/wave)
        int lane = tid & 63, wv = tid >> 6;
        int row = (b - 7054)*4 + wv;
        const float* wr = W4 + (size_t)row * 512;
        float s = 0.f;
#pragma unroll
        for (int i = 0; i < 8; ++i) s += wr[lane + 64*i] * Ww[lane + 64*i];
#pragma unroll
        for (int off = 32; off; off >>= 1) s += __shfl_xor(s, off);
        if (lane == 0) t1out[row] = s;
    }
}

// ---------------- attention (h-independent) ----------------
__global__ __launch_bounds__(512) void attn_ctx(const float* __restrict__ enc,
                                                const float* __restrict__ weff,
                                                float* __restrict__ ctx){
    __shared__ float att[S_];
    int b = blockIdx.x, tid = threadIdx.x;
    int wv = tid >> 6, lane = tid & 63;
    float w8[8];
#pragma unroll
    for (int i = 0; i < 8; ++i) w8[i] = weff[lane + 64*i];
    const float* eb = enc + (size_t)b * (S_*H_);
    for (int s = wv; s < S_; s += 8){
        const float* e = eb + s*512;
        float acc = 0.f;
#pragma unroll
        for (int i = 0; i < 8; ++i) acc += e[lane + 64*i] * w8[i];
#pragma unroll
        for (int off = 32; off; off >>= 1) acc += __shfl_xor(acc, off);
        if (lane == 0) att[s] = acc;
    }
    __syncthreads();
    if (tid == 0){
        float mx = att[0];
        for (int s = 1; s < S_; ++s) mx = fmaxf(mx, att[s]);
        float sum = 0.f;
        for (int s = 0; s < S_; ++s){ float e = expf(att[s] - mx); att[s] = e; sum += e; }
        float inv = 1.f / sum;
        for (int s = 0; s < S_; ++s) att[s] *= inv;
    }
    __syncthreads();
    float a = 0.f;
    for (int s = 0; s < S_; ++s) a += att[s] * eb[s*512 + tid];
    ctx[b*512 + tid] = a;
}

// ---------------- shared 64-row step body (used by front3 gh0 branch) ----------------
__device__ __forceinline__ void step_mm_body(char* smem, int m0, int nt, int n_logits,
    const u16* __restrict__ Ahg, const u16* __restrict__ Alg,
    const u16* __restrict__ WoHi, const u16* __restrict__ WoLo,
    const u16* __restrict__ WhhHi, const u16* __restrict__ WhhLo,
    const float* __restrict__ bo,
    float* __restrict__ logits, unsigned long long* __restrict__ Pcur,
    float* __restrict__ gh_out)
{
    u16 (*Ah)[2048] = (u16(*)[2048])(smem);
    u16 (*Al)[2048] = (u16(*)[2048])(smem + 8192);
    u16 (*Bh)[2048] = (u16(*)[2048])(smem + 16384);
    u16 (*Bl)[2048] = (u16(*)[2048])(smem + 24576);
    bool isL = nt < n_logits;
    int nbase = (isL ? nt : nt - n_logits) * 64;
    const u16* Bhg = isL ? WoHi : WhhHi;
    const u16* Blg = isL ? WoLo : WhhLo;
    int tid = threadIdx.x, lane = tid & 63, wid = tid >> 6;
    int wy = wid & 1, wx = wid >> 1;
    int l15 = lane & 15, rg = lane >> 4, lk = rg * 8;
    int sr = tid >> 2, sk8 = (tid & 3) * 8;

    const u16* gAh = Ahg + (size_t)(m0 + sr)*512 + sk8;
    const u16* gAl = Alg + (size_t)(m0 + sr)*512 + sk8;
    const u16* gBh = Bhg + (size_t)(nbase + sr)*512 + sk8;
    const u16* gBl = Blg + (size_t)(nbase + sr)*512 + sk8;

    *(short8v*)&Ah[0][tid*8] = *(const short8v*)gAh;
    *(short8v*)&Al[0][tid*8] = *(const short8v*)gAl;
    *(short8v*)&Bh[0][tid*8] = *(const short8v*)gBh;
    *(short8v*)&Bl[0][tid*8] = *(const short8v*)gBl;
    short8v r1a = *(const short8v*)(gAh + 32), r1b = *(const short8v*)(gAl + 32);
    short8v r1c = *(const short8v*)(gBh + 32), r1d = *(const short8v*)(gBl + 32);
    short8v r2a = *(const short8v*)(gAh + 64), r2b = *(const short8v*)(gAl + 64);
    short8v r2c = *(const short8v*)(gBh + 64), r2d = *(const short8v*)(gBl + 64);
    __syncthreads();

    f32x4 acc[2][2] = {};
    int p = 0;
    for (int k0 = 0; k0 < 512; k0 += 32){
        if (k0 + 32 < 512){
            *(short8v*)&Ah[p^1][tid*8] = r1a;
            *(short8v*)&Al[p^1][tid*8] = r1b;
            *(short8v*)&Bh[p^1][tid*8] = r1c;
            *(short8v*)&Bl[p^1][tid*8] = r1d;
            r1a = r2a; r1b = r2b; r1c = r2c; r1d = r2d;
            if (k0 + 96 < 512){
                r2a = *(const short8v*)(gAh + k0 + 96);
                r2b = *(const short8v*)(gAl + k0 + 96);
                r2c = *(const short8v*)(gBh + k0 + 96);
                r2d = *(const short8v*)(gBl + k0 + 96);
            }
        }
        short8v afh0 = *(const short8v*)&Ah[p][(wy*32 +  0 + l15)*32 + lk];
        short8v afh1 = *(const short8v*)&Ah[p][(wy*32 + 16 + l15)*32 + lk];
        short8v afl0 = *(const short8v*)&Al[p][(wy*32 +  0 + l15)*32 + lk];
        short8v afl1 = *(const short8v*)&Al[p][(wy*32 + 16 + l15)*32 + lk];
        short8v bfh0 = *(const short8v*)&Bh[p][(wx*32 +  0 + l15)*32 + lk];
        short8v bfh1 = *(const short8v*)&Bh[p][(wx*32 + 16 + l15)*32 + lk];
        short8v bfl0 = *(const short8v*)&Bl[p][(wx*32 +  0 + l15)*32 + lk];
        short8v bfl1 = *(const short8v*)&Bl[p][(wx*32 + 16 + l15)*32 + lk];
        MFMA3(acc[0][0], afh0, afl0, bfh0, bfl0);
        MFMA3(acc[0][1], afh0, afl0, bfh1, bfl1);
        MFMA3(acc[1][0], afh1, afl1, bfh0, bfl0);
        MFMA3(acc[1][1], afh1, afl1, bfh1, bfl1);
        __syncthreads();
        p ^= 1;
    }

    int col0 = nbase + wx*32 + l15;
    if (isL){
        float bo0 = bo[col0], bo1 = bo[col0 + 16];
#pragma unroll
        for (int mf = 0; mf < 2; ++mf){
#pragma unroll
            for (int r = 0; r < 4; ++r){
                int row = m0 + wy*32 + mf*16 + rg*4 + r;
                float v0 = acc[mf][0][r] + bo0;
                float v1 = acc[mf][1][r] + bo1;
                float* crow = logits + (size_t)row * (NSTEP * (size_t)V_);
                crow[col0]      = v0;
                crow[col0 + 16] = v1;
                unsigned long long k0_ = ((unsigned long long)fkey(v0) << 32) | (unsigned)(4095 - col0);
                unsigned long long k1_ = ((unsigned long long)fkey(v1) << 32) | (unsigned)(4095 - (col0+16));
                unsigned long long best = k0_ > k1_ ? k0_ : k1_;
#pragma unroll
                for (int off = 1; off < 16; off <<= 1){
                    unsigned long long o = __shfl_xor(best, off);
                    if (o > best) best = o;
                }
                if (l15 == 0) atomicMax(&Pcur[row], best);
            }
        }
    } else {
#pragma unroll
        for (int mf = 0; mf < 2; ++mf)
#pragma unroll
            for (int r = 0; r < 4; ++r){
                int row = m0 + wy*32 + mf*16 + rg*4 + r;
                gh_out[(size_t)row*1536 + col0]      = acc[mf][0][r];
                gh_out[(size_t)row*1536 + col0 + 16] = acc[mf][1][r];
            }
    }
}

// ---------------- front3: eproj(128x128, dbuf, XCD-swizzled) U gictx U gh0 ----------------
__global__ __launch_bounds__(256) void front3(
    const u16* __restrict__ EmbHi, const u16* __restrict__ EmbLo,
    const u16* __restrict__ WihLHi, const u16* __restrict__ WihLLo,
    float* __restrict__ Eproj,
    const float* __restrict__ ctx, const float* __restrict__ WihR,
    const float* __restrict__ bih, float* __restrict__ gictx,
    const u16* __restrict__ Sh0, const u16* __restrict__ Sl0,
    const u16* __restrict__ WhhHi, const u16* __restrict__ WhhLo,
    float* __restrict__ gh0)
{
    __shared__ __align__(16) char smem[65536];
    int b = blockIdx.x, tid = threadIdx.x;
    if (b < 384){
        int work = (b & 7) * 48 + (b >> 3);   // 384 = 8 * 48, bijective
        int bm = work / 12, bn = work % 12;
        int n0 = bn * 128, m0 = bm * 128;
        int lane = tid & 63, wid = tid >> 6;
        int wy = wid & 1, wx = wid >> 1;
        int l15 = lane & 15, rg = lane >> 4, lk = rg * 8;
        u16* AhB = (u16*)smem;                 // [2][4096]
        u16* AlB = (u16*)(smem + 16384);
        u16* BhB = (u16*)(smem + 32768);
        u16* BlB = (u16*)(smem + 49152);
        const u16* gA[2][2]; const u16* gB[2][2];
        int s8i[2];
#pragma unroll
        for (int j = 0; j < 2; ++j){
            int s = tid + j*256;
            int row = s >> 2, k8 = (s & 3)*8;
            s8i[j] = s * 8;
            gA[0][j] = EmbHi + (size_t)(m0+row)*1024 + k8;
            gA[1][j] = EmbLo + (size_t)(m0+row)*1024 + k8;
            gB[0][j] = WihLHi + (size_t)(n0+row)*1024 + k8;
            gB[1][j] = WihLLo + (size_t)(n0+row)*1024 + k8;
        }
        // stage chunk 0 directly; prefetch chunks 1,2 into regs
#pragma unroll
        for (int j = 0; j < 2; ++j){
            *(short8v*)&AhB[s8i[j]] = *(const short8v*)gA[0][j];
            *(short8v*)&AlB[s8i[j]] = *(const short8v*)gA[1][j];
            *(short8v*)&BhB[s8i[j]] = *(const short8v*)gB[0][j];
            *(short8v*)&BlB[s8i[j]] = *(const short8v*)gB[1][j];
        }
        short8v r1A[2][2], r1B[2][2], r2A[2][2], r2B[2][2];
#pragma unroll
        for (int h = 0; h < 2; ++h)
#pragma unroll
            for (int j = 0; j < 2; ++j){
                r1A[h][j] = *(const short8v*)(gA[h][j] + 32);
                r1B[h][j] = *(const short8v*)(gB[h][j] + 32);
                r2A[h][j] = *(const short8v*)(gA[h][j] + 64);
                r2B[h][j] = *(const short8v*)(gB[h][j] + 64);
            }
        __syncthreads();
        f32x4 acc[4][4] = {};
        int p = 0;
        for (int k0 = 0; k0 < 1024; k0 += 32){
            if (k0 + 32 < 1024){
                int off = (p^1)*4096;
#pragma unroll
                for (int j = 0; j < 2; ++j){
                    *(short8v*)&AhB[off + s8i[j]] = r1A[0][j];
                    *(short8v*)&AlB[off + s8i[j]] = r1A[1][j];
                    *(short8v*)&BhB[off + s8i[j]] = r1B[0][j];
                    *(short8v*)&BlB[off + s8i[j]] = r1B[1][j];
                }
#pragma unroll
                for (int h = 0; h < 2; ++h)
#pragma unroll
                    for (int j = 0; j < 2; ++j){
                        r1A[h][j] = r2A[h][j];
                        r1B[h][j] = r2B[h][j];
                    }
                if (k0 + 96 < 1024){
#pragma unroll
                    for (int h = 0; h < 2; ++h)
#pragma unroll
                        for (int j = 0; j < 2; ++j){
                            r2A[h][j] = *(const short8v*)(gA[h][j] + k0 + 96);
                            r2B[h][j] = *(const short8v*)(gB[h][j] + k0 + 96);
                        }
                }
            }
            int base = p*4096;
            short8v afh[4], afl[4];
#pragma unroll
            for (int mf = 0; mf < 4; ++mf){
                afh[mf] = *(const short8v*)&AhB[base + (wy*64 + mf*16 + l15)*32 + lk];
                afl[mf] = *(const short8v*)&AlB[base + (wy*64 + mf*16 + l15)*32 + lk];
            }
#pragma unroll
            for (int nf = 0; nf < 4; ++nf){
                short8v bfh = *(const short8v*)&BhB[base + (wx*64 + nf*16 + l15)*32 + lk];
                short8v bfl = *(const short8v*)&BlB[base + (wx*64 + nf*16 + l15)*32 + lk];
#pragma unroll
                for (int mf = 0; mf < 4; ++mf)
                    MFMA3(acc[mf][nf], afh[mf], afl[mf], bfh, bfl);
            }
            __syncthreads();
            p ^= 1;
        }
        int col0 = n0 + wx*64 + l15;
#pragma unroll
        for (int mf = 0; mf < 4; ++mf)
#pragma unroll
            for (int r = 0; r < 4; ++r){
                int row = m0 + wy*64 + mf*16 + rg*4 + r;
#pragma unroll
                for (int nf = 0; nf < 4; ++nf)
                    Eproj[(size_t)row*1536 + col0 + nf*16] = acc[mf][nf][r];
            }
    } else if (b < 576){
        int lb = b - 384;
        int m0 = (lb & 7) * 32, n0 = (lb >> 3) * 64;
        float (*As)[36] = (float(*)[36])smem;
        float (*Bs)[68] = (float(*)[68])(smem + 2304);
        int lk = tid & 15, lr = tid >> 4;
        int tx = tid & 15, ty = tid >> 4;
        float c[2][4] = {};
        for (int k0 = 0; k0 < 512; k0 += 16){
#pragma unroll
            for (int i = 0; i < 2; ++i)
                As[lk][lr*2 + i] = ctx[(size_t)(m0 + lr*2 + i)*512 + k0 + lk];
#pragma unroll
            for (int i = 0; i < 4; ++i)
                Bs[lk][lr*4 + i] = WihR[(size_t)(n0 + lr*4 + i)*1536 + k0 + lk];
            __syncthreads();
#pragma unroll
            for (int k = 0; k < 16; ++k){
                float b4[4];
                *(float4*)b4 = *(const float4*)&Bs[k][tx*4];
#pragma unroll
                for (int i = 0; i < 2; ++i){
                    float a = As[k][ty*2 + i];
#pragma unroll
                    for (int j = 0; j < 4; ++j) c[i][j] += a * b4[j];
                }
            }
            __syncthreads();
        }
#pragma unroll
        for (int j = 0; j < 4; ++j){
            float bb = bih[n0 + tx*4 + j];
#pragma unroll
            for (int i = 0; i < 2; ++i)
                gictx[(size_t)(m0 + ty*2 + i)*1536 + n0 + tx*4 + j] = c[i][j] + bb;
        }
    } else {
        int lb = b - 576;
        step_mm_body(smem, (lb & 3)*64, lb >> 2, 0,
                     Sh0, Sl0, nullptr, nullptr, WhhHi, WhhLo,
                     nullptr, nullptr, nullptr, gh0);
    }
}

// ---------------- per-step kernels ----------------
__global__ __launch_bounds__(128) void gru_pointwise(
    const float* __restrict__ gh, const float* __restrict__ Eproj,
    const float* __restrict__ gictx, const float* __restrict__ bhh,
    const float* __restrict__ hprev, float* __restrict__ hnext,
    u16* __restrict__ Sh, u16* __restrict__ Sl,
    const unsigned long long* __restrict__ Pprev,
    float* __restrict__ preds, int t)
{
    int tid = threadIdx.x;
    int row = blockIdx.x;
    int jj = tid * 4;
    int w = 1;
    if (t > 0){
        w = 4095 - (int)(Pprev[row] & 0xFFFFFFFFull);
        if (w < 0) w = 0; if (w > 4095) w = 4095;
        if (tid == 0) preds[row*NSTEP + (t-1)] = (float)w;
    }
    const float* gr = gh + (size_t)row * 1536;
    const float* ep = Eproj + (size_t)w * 1536;
    const float* gc = gictx + (size_t)row * 1536;
    float4 g0 = *(const float4*)&gr[jj];
    float4 g1 = *(const float4*)&gr[512 + jj];
    float4 g2 = *(const float4*)&gr[1024 + jj];
    float4 e0 = *(const float4*)&ep[jj];
    float4 e1 = *(const float4*)&ep[512 + jj];
    float4 e2 = *(const float4*)&ep[1024 + jj];
    float4 c0 = *(const float4*)&gc[jj];
    float4 c1 = *(const float4*)&gc[512 + jj];
    float4 c2 = *(const float4*)&gc[1024 + jj];
    float4 b0 = *(const float4*)&bhh[jj];
    float4 b1 = *(const float4*)&bhh[512 + jj];
    float4 b2 = *(const float4*)&bhh[1024 + jj];
    float4 ho = *(const float4*)&hprev[(size_t)row*512 + jj];
    const float* G0 = (const float*)&g0; const float* G1 = (const float*)&g1;
    const float* G2 = (const float*)&g2;
    const float* E0 = (const float*)&e0; const float* E1 = (const float*)&e1;
    const float* E2 = (const float*)&e2;
    const float* C0 = (const float*)&c0; const float* C1 = (const float*)&c1;
    const float* C2 = (const float*)&c2;
    const float* B0 = (const float*)&b0; const float* B1 = (const float*)&b1;
    const float* B2 = (const float*)&b2;
    const float* HO = (const float*)&ho;
    float4 res;
    float* R = (float*)&res;
#pragma unroll
    for (int i = 0; i < 4; ++i){
        float gir = E0[i] + C0[i] + G0[i] + B0[i];
        float giz = E1[i] + C1[i] + G1[i] + B1[i];
        float gin = E2[i] + C2[i];
        float rr = 1.f / (1.f + expf(-gir));
        float zz = 1.f / (1.f + expf(-giz));
        float nn = tanhf(gin + rr * (G2[i] + B2[i]));
        R[i] = (1.f - zz)*nn + zz*HO[i];
    }
    size_t o = (size_t)row*512 + jj;
    *(float4*)&hnext[o] = res;
    ushort4v h4, l4; split_f4(res, h4, l4);
    *(ushort4v*)&Sh[o] = h4;
    *(ushort4v*)&Sl[o] = l4;
}

// 32-row x 64-col tiles, 704 blocks (2.75/CU), XCD-swizzled.
__global__ __launch_bounds__(256) void step_mm(
    const u16* __restrict__ Ahg, const u16* __restrict__ Alg,
    const u16* __restrict__ WoHi, const u16* __restrict__ WoLo,
    const u16* __restrict__ WhhHi, const u16* __restrict__ WhhLo,
    const float* __restrict__ bo,
    float* __restrict__ logits, unsigned long long* __restrict__ Pcur,
    float* __restrict__ gh_out, int n_logits)
{
    __shared__ __align__(16) char smem[24576];
    u16 (*Ah)[1024] = (u16(*)[1024])(smem);
    u16 (*Al)[1024] = (u16(*)[1024])(smem + 4096);
    u16 (*Bh)[2048] = (u16(*)[2048])(smem + 8192);
    u16 (*Bl)[2048] = (u16(*)[2048])(smem + 16384);
    int bid = blockIdx.x;
    int work = (bid & 7) * 88 + (bid >> 3);
    int m0 = (work & 7) * 32;
    int nt = work >> 3;
    bool isL = nt < n_logits;
    int nbase = (isL ? nt : nt - n_logits) * 64;
    const u16* Bhg = isL ? WoHi : WhhHi;
    const u16* Blg = isL ? WoLo : WhhLo;
    int tid = threadIdx.x, lane = tid & 63, wid = tid >> 6;
    int wy = wid & 1, wx = wid >> 1;
    int l15 = lane & 15, rg = lane >> 4, lk = rg * 8;

    int ahalf = tid >> 7, ai = tid & 127;
    int ar = ai >> 2, ak8 = (ai & 3) * 8;
    const u16* gA = (ahalf ? Alg : Ahg) + (size_t)(m0 + ar)*512 + ak8;
    u16 (*Adst)[1024] = ahalf ? Al : Ah;
    int br = tid >> 2, bk8 = (tid & 3) * 8;
    const u16* gBh = Bhg + (size_t)(nbase + br)*512 + bk8;
    const u16* gBl = Blg + (size_t)(nbase + br)*512 + bk8;

    *(short8v*)&Adst[0][ai*8] = *(const short8v*)gA;
    *(short8v*)&Bh[0][tid*8] = *(const short8v*)gBh;
    *(short8v*)&Bl[0][tid*8] = *(const short8v*)gBl;
    short8v a1 = *(const short8v*)(gA + 32),  a2 = *(const short8v*)(gA + 64);
    short8v h1 = *(const short8v*)(gBh + 32), h2 = *(const short8v*)(gBh + 64);
    short8v l1 = *(const short8v*)(gBl + 32), l2 = *(const short8v*)(gBl + 64);
    __syncthreads();

    f32x4 acc[2] = {};
    int p = 0;
    for (int k0 = 0; k0 < 512; k0 += 32){
        if (k0 + 32 < 512){
            *(short8v*)&Adst[p^1][ai*8] = a1;
            *(short8v*)&Bh[p^1][tid*8] = h1;
            *(short8v*)&Bl[p^1][tid*8] = l1;
            a1 = a2; h1 = h2; l1 = l2;
            if (k0 + 96 < 512){
                a2 = *(const short8v*)(gA + k0 + 96);
                h2 = *(const short8v*)(gBh + k0 + 96);
                l2 = *(const short8v*)(gBl + k0 + 96);
            }
        }
        short8v afh = *(const short8v*)&Ah[p][(wy*16 + l15)*32 + lk];
        short8v afl = *(const short8v*)&Al[p][(wy*16 + l15)*32 + lk];
        short8v bfh0 = *(const short8v*)&Bh[p][(wx*32 +  0 + l15)*32 + lk];
        short8v bfh1 = *(const short8v*)&Bh[p][(wx*32 + 16 + l15)*32 + lk];
        short8v bfl0 = *(const short8v*)&Bl[p][(wx*32 +  0 + l15)*32 + lk];
        short8v bfl1 = *(const short8v*)&Bl[p][(wx*32 + 16 + l15)*32 + lk];
        MFMA3(acc[0], afh, afl, bfh0, bfl0);
        MFMA3(acc[1], afh, afl, bfh1, bfl1);
        __syncthreads();
        p ^= 1;
    }

    int col0 = nbase + wx*32 + l15;
    if (isL){
        float bo0 = bo[col0], bo1 = bo[col0 + 16];
#pragma unroll
        for (int r = 0; r < 4; ++r){
            int row = m0 + wy*16 + rg*4 + r;
            float v0 = acc[0][r] + bo0;
            float v1 = acc[1][r] + bo1;
            float* crow = logits + (size_t)row * (NSTEP * (size_t)V_);
            crow[col0]      = v0;
            crow[col0 + 16] = v1;
            unsigned long long k0_ = ((unsigned long long)fkey(v0) << 32) | (unsigned)(4095 - col0);
            unsigned long long k1_ = ((unsigned long long)fkey(v1) << 32) | (unsigned)(4095 - (col0+16));
            unsigned long long best = k0_ > k1_ ? k0_ : k1_;
#pragma unroll
            for (int off = 1; off < 16; off <<= 1){
                unsigned long long o = __shfl_xor(best, off);
                if (o > best) best = o;
            }
            if (l15 == 0) atomicMax(&Pcur[row], best);
        }
    } else {
#pragma unroll
        for (int r = 0; r < 4; ++r){
            int row = m0 + wy*16 + rg*4 + r;
            gh_out[(size_t)row*1536 + col0]      = acc[0][r];
            gh_out[(size_t)row*1536 + col0 + 16] = acc[1][r];
        }
    }
}

__global__ __launch_bounds__(256) void final_pred(const unsigned long long* __restrict__ P,
                                                  float* __restrict__ preds){
    int b = threadIdx.x;
    int w = 4095 - (int)(P[b] & 0xFFFFFFFFull);
    if (w < 0) w = 0; if (w > 4095) w = 4095;
    preds[b*NSTEP + (NSTEP-1)] = (float)w;
}

extern "C" void kernel_launch(void* const* d_in, const int* in_sizes, int n_in,
                              void* d_out, int out_size, void* d_ws, size_t ws_size,
                              hipStream_t stream){
    const float* elhs = (const float*)d_in[0];
    const float* enc  = (const float*)d_in[1];
    const float* emb  = (const float*)d_in[3];
    const float* W1   = (const float*)d_in[4];
    const float* W2   = (const float*)d_in[6];
    const float* W3   = (const float*)d_in[8];
    const float* W4   = (const float*)d_in[10];
    const float* Ww   = (const float*)d_in[12];
    const float* Wih  = (const float*)d_in[13];
    const float* bih  = (const float*)d_in[14];
    const float* Whh  = (const float*)d_in[15];
    const float* bhh  = (const float*)d_in[16];
    const float* Wo   = (const float*)d_in[17];
    const float* bo   = (const float*)d_in[18];

    float* out = (float*)d_out;
    float* preds = out + (size_t)B_ * NSTEP * V_;

    float* ws = (float*)d_ws;
    float* Eproj  = ws;  ws += (size_t)V_ * 1536;
    float* gictx  = ws;  ws += (size_t)B_ * 1536;
    float* ctx    = ws;  ws += B_ * H_;
    float* t1     = ws;  ws += 512;
    float* t2     = ws;  ws += 512;
    float* weff   = ws;  ws += 512;
    float* Hf     = ws;  ws += 2 * B_ * H_;
    float* ghbuf  = ws;  ws += B_ * 1536;
    u16* WoT_hi = (u16*)ws;  ws += (size_t)V_ * 512 / 2;
    u16* WoT_lo = (u16*)ws;  ws += (size_t)V_ * 512 / 2;
    u16* WhhHi  = (u16*)ws;  ws += 1536 * 512 / 2;
    u16* WhhLo  = (u16*)ws;  ws += 1536 * 512 / 2;
    u16* Sh     = (u16*)ws;  ws += B_ * H_ / 2;
    u16* Sl     = (u16*)ws;  ws += B_ * H_ / 2;
    unsigned long long* P = (unsigned long long*)ws;   // 27*256 u64

    // big one-time splits parked in d_out head (consumed by front3 before logits writes)
    u16* EmbHi  = (u16*)d_out;
    u16* EmbLo  = EmbHi + (size_t)V_*1024;
    u16* WihLHi = EmbLo + (size_t)V_*1024;
    u16* WihLLo = WihLHi + (size_t)1536*1024;

    prep_all<<<7182, 256, 0, stream>>>(Whh, Wo, emb, Wih, elhs, W4, Ww,
                                       WhhHi, WhhLo, WoT_hi, WoT_lo,
                                       EmbHi, EmbLo, WihLHi, WihLLo,
                                       Sh, Sl, t1, (unsigned*)P, NSTEP*256*2);
    matvec512<<<512, 64, 0, stream>>>(W3, t1, t2);
    matvec512<<<512, 64, 0, stream>>>(W2, t2, t1);
    matvec512<<<512, 64, 0, stream>>>(W1, t1, weff);
    attn_ctx<<<B_, 512, 0, stream>>>(enc, weff, ctx);
    front3<<<672, 256, 0, stream>>>(EmbHi, EmbLo, WihLHi, WihLLo, Eproj,
                                    ctx, Wih + 1024, bih, gictx,
                                    Sh, Sl, WhhHi, WhhLo, ghbuf);

    for (int t = 0; t < NSTEP; ++t){
        const float* hr = (t == 0) ? elhs : (Hf + (size_t)((t-1) & 1) * (B_*H_));
        float*       hw = Hf + (size_t)(t & 1) * (B_*H_);
        const unsigned long long* Pprev = P + (size_t)(t > 0 ? t-1 : 0) * 256;
        gru_pointwise<<<256, 128, 0, stream>>>(ghbuf, Eproj, gictx, bhh, hr, hw,
                                               Sh, Sl, Pprev, preds, t);
        step_mm<<<704, 256, 0, stream>>>(Sh, Sl, WoT_hi, WoT_lo, WhhHi, WhhLo, bo,
                                         out + (size_t)t * V_, P + (size_t)t*256, ghbuf, 64);
    }
    final_pred<<<1, 256, 0, stream>>>(P + (size_t)(NSTEP-1)*256, preds);
}

// Round 17
// 689.380 us; speedup vs baseline: 1.0074x; 1.0074x over previous
//
#include <hip/hip_runtime.h>

#define B_ 256
#define S_ 80
#define H_ 512
#define V_ 4096
#define NSTEP 27

typedef unsigned short u16;
typedef __attribute__((ext_vector_type(8))) short short8v;
typedef __attribute__((ext_vector_type(4))) float f32x4;
typedef __attribute__((ext_vector_type(4))) unsigned short ushort4v;

#define MFMA_(a,b,c) __builtin_amdgcn_mfma_f32_16x16x32_bf16(a,b,c,0,0,0)
#define MFMA3(acc, ah, al, bh, bl) do{ acc = MFMA_(ah,bh,acc); acc = MFMA_(ah,bl,acc); acc = MFMA_(al,bh,acc);}while(0)

__device__ __forceinline__ unsigned fkey(float v){
    unsigned u = __float_as_uint(v);
    return (u & 0x80000000u) ? ~u : (u | 0x80000000u);
}
__device__ __forceinline__ u16 bf16_rne(float f){
    unsigned u = __float_as_uint(f);
    return (u16)((u + 0x7FFFu + ((u >> 16) & 1u)) >> 16);
}
__device__ __forceinline__ void split_f4(float4 v, ushort4v& hi, ushort4v& lo){
    float arr[4] = {v.x, v.y, v.z, v.w};
    ushort4v h, l;
#pragma unroll
    for (int i = 0; i < 4; ++i){
        u16 hb = bf16_rne(arr[i]);
        h[i] = hb;
        l[i] = bf16_rne(arr[i] - __uint_as_float(((unsigned)hb) << 16));
    }
    hi = h; lo = l;
}

// ---------------- small matvec (weff chain) ----------------
__global__ __launch_bounds__(64) void matvec512(const float* __restrict__ W,
                                                const float* __restrict__ v,
                                                float* __restrict__ out){
    int row = blockIdx.x, lane = threadIdx.x;
    const float* wr = W + row * 512;
    float s = 0.f;
#pragma unroll
    for (int i = 0; i < 8; ++i) s += wr[lane + 64*i] * v[lane + 64*i];
#pragma unroll
    for (int off = 32; off; off >>= 1) s += __shfl_xor(s, off);
    if (lane == 0) out[row] = s;
}

// ---------------- one-time transforms (+ t1 = W4@Ww stage) ----------------
__global__ __launch_bounds__(256) void prep_all(
    const float* __restrict__ Whh, const float* __restrict__ Wo,
    const float* __restrict__ emb, const float* __restrict__ Wih,
    const float* __restrict__ elhs,
    const float* __restrict__ W4, const float* __restrict__ Ww,
    u16* __restrict__ WhhHi, u16* __restrict__ WhhLo,
    u16* __restrict__ WoThi, u16* __restrict__ WoTlo,
    u16* __restrict__ EmbHi, u16* __restrict__ EmbLo,
    u16* __restrict__ WihLHi, u16* __restrict__ WihLLo,
    u16* __restrict__ Sh, u16* __restrict__ Sl,
    float* __restrict__ t1out,
    unsigned* __restrict__ zp, int nz)
{
    __shared__ float T[64][65];
    int b = blockIdx.x, tid = threadIdx.x;
    if (b < 768){
        int idx = (b*256 + tid)*4;
        float4 v = *(const float4*)&Whh[idx];
        ushort4v h,l; split_f4(v,h,l);
        *(ushort4v*)&WhhHi[idx]=h; *(ushort4v*)&WhhLo[idx]=l;
    } else if (b < 1280){
        int lb = b - 768;
        int k0 = (lb & 7)*64, n0 = (lb >> 3)*64;
#pragma unroll
        for (int i = 0; i < 16; ++i){
            int idx = tid + i*256;
            int kk = idx >> 6, nn = idx & 63;
            T[kk][nn] = Wo[(size_t)(k0+kk)*4096 + n0+nn];
        }
        __syncthreads();
#pragma unroll
        for (int i = 0; i < 16; ++i){
            int idx = tid + i*256;
            int nn = idx >> 6, kk = idx & 63;
            float v = T[kk][nn];
            u16 hi = bf16_rne(v);
            u16 lo = bf16_rne(v - __uint_as_float(((unsigned)hi) << 16));
            size_t o = (size_t)(n0+nn)*512 + k0+kk;
            WoThi[o] = hi; WoTlo[o] = lo;
        }
    } else if (b < 5376){
        int idx = ((b-1280)*256 + tid)*4;
        float4 v = *(const float4*)&emb[idx];
        ushort4v h,l; split_f4(v,h,l);
        *(ushort4v*)&EmbHi[idx]=h; *(ushort4v*)&EmbLo[idx]=l;
    } else if (b < 6912){
        int id = ((b-5376)*256 + tid)*4;
        int r = id >> 10, c = id & 1023;
        float4 v = *(const float4*)&Wih[(size_t)r*1536 + c];
        ushort4v h,l; split_f4(v,h,l);
        *(ushort4v*)&WihLHi[id]=h; *(ushort4v*)&WihLLo[id]=l;
    } else if (b < 7040){
        int idx = ((b-6912)*256 + tid)*4;
        float4 v = *(const float4*)&elhs[idx];
        ushort4v h,l; split_f4(v,h,l);
        *(ushort4v*)&Sh[idx]=h; *(ushort4v*)&Sl[idx]=l;
    } else if (b < 7054){
        int i = ((b-7040)*256 + tid)*4;
        if (i < nz){ zp[i]=0u; zp[i+1]=0u; zp[i+2]=0u; zp[i+3]=0u; }
    } else {
        // t1 = W4 @ Ww : 128 blocks x 4 rows (4 waves/block, 1 row/wave)
        int lane = tid & 63, wv = tid >> 6;
        int row = (b - 7054)*4 + wv;
        const float* wr = W4 + (size_t)row * 512;
        float s = 0.f;
#pragma unroll
        for (int i = 0; i < 8; ++i) s += wr[lane + 64*i] * Ww[lane + 64*i];
#pragma unroll
        for (int off = 32; off; off >>= 1) s += __shfl_xor(s, off);
        if (lane == 0) t1out[row] = s;
    }
}

// ---------------- attention (h-independent) ----------------
__global__ __launch_bounds__(512) void attn_ctx(const float* __restrict__ enc,
                                                const float* __restrict__ weff,
                                                float* __restrict__ ctx){
    __shared__ float att[S_];
    int b = blockIdx.x, tid = threadIdx.x;
    int wv = tid >> 6, lane = tid & 63;
    float w8[8];
#pragma unroll
    for (int i = 0; i < 8; ++i) w8[i] = weff[lane + 64*i];
    const float* eb = enc + (size_t)b * (S_*H_);
    for (int s = wv; s < S_; s += 8){
        const float* e = eb + s*512;
        float acc = 0.f;
#pragma unroll
        for (int i = 0; i < 8; ++i) acc += e[lane + 64*i] * w8[i];
#pragma unroll
        for (int off = 32; off; off >>= 1) acc += __shfl_xor(acc, off);
        if (lane == 0) att[s] = acc;
    }
    __syncthreads();
    if (tid == 0){
        float mx = att[0];
        for (int s = 1; s < S_; ++s) mx = fmaxf(mx, att[s]);
        float sum = 0.f;
        for (int s = 0; s < S_; ++s){ float e = expf(att[s] - mx); att[s] = e; sum += e; }
        float inv = 1.f / sum;
        for (int s = 0; s < S_; ++s) att[s] *= inv;
    }
    __syncthreads();
    float a = 0.f;
    for (int s = 0; s < S_; ++s) a += att[s] * eb[s*512 + tid];
    ctx[b*512 + tid] = a;
}

// ---------------- shared 64-row step body (used by front3 gh0 branch) ----------------
__device__ __forceinline__ void step_mm_body(char* smem, int m0, int nt, int n_logits,
    const u16* __restrict__ Ahg, const u16* __restrict__ Alg,
    const u16* __restrict__ WoHi, const u16* __restrict__ WoLo,
    const u16* __restrict__ WhhHi, const u16* __restrict__ WhhLo,
    const float* __restrict__ bo,
    float* __restrict__ logits, unsigned long long* __restrict__ Pcur,
    float* __restrict__ gh_out)
{
    u16 (*Ah)[2048] = (u16(*)[2048])(smem);
    u16 (*Al)[2048] = (u16(*)[2048])(smem + 8192);
    u16 (*Bh)[2048] = (u16(*)[2048])(smem + 16384);
    u16 (*Bl)[2048] = (u16(*)[2048])(smem + 24576);
    bool isL = nt < n_logits;
    int nbase = (isL ? nt : nt - n_logits) * 64;
    const u16* Bhg = isL ? WoHi : WhhHi;
    const u16* Blg = isL ? WoLo : WhhLo;
    int tid = threadIdx.x, lane = tid & 63, wid = tid >> 6;
    int wy = wid & 1, wx = wid >> 1;
    int l15 = lane & 15, rg = lane >> 4, lk = rg * 8;
    int sr = tid >> 2, sk8 = (tid & 3) * 8;

    const u16* gAh = Ahg + (size_t)(m0 + sr)*512 + sk8;
    const u16* gAl = Alg + (size_t)(m0 + sr)*512 + sk8;
    const u16* gBh = Bhg + (size_t)(nbase + sr)*512 + sk8;
    const u16* gBl = Blg + (size_t)(nbase + sr)*512 + sk8;

    *(short8v*)&Ah[0][tid*8] = *(const short8v*)gAh;
    *(short8v*)&Al[0][tid*8] = *(const short8v*)gAl;
    *(short8v*)&Bh[0][tid*8] = *(const short8v*)gBh;
    *(short8v*)&Bl[0][tid*8] = *(const short8v*)gBl;
    short8v r1a = *(const short8v*)(gAh + 32), r1b = *(const short8v*)(gAl + 32);
    short8v r1c = *(const short8v*)(gBh + 32), r1d = *(const short8v*)(gBl + 32);
    short8v r2a = *(const short8v*)(gAh + 64), r2b = *(const short8v*)(gAl + 64);
    short8v r2c = *(const short8v*)(gBh + 64), r2d = *(const short8v*)(gBl + 64);
    __syncthreads();

    f32x4 acc[2][2] = {};
    int p = 0;
    for (int k0 = 0; k0 < 512; k0 += 32){
        if (k0 + 32 < 512){
            *(short8v*)&Ah[p^1][tid*8] = r1a;
            *(short8v*)&Al[p^1][tid*8] = r1b;
            *(short8v*)&Bh[p^1][tid*8] = r1c;
            *(short8v*)&Bl[p^1][tid*8] = r1d;
            r1a = r2a; r1b = r2b; r1c = r2c; r1d = r2d;
            if (k0 + 96 < 512){
                r2a = *(const short8v*)(gAh + k0 + 96);
                r2b = *(const short8v*)(gAl + k0 + 96);
                r2c = *(const short8v*)(gBh + k0 + 96);
                r2d = *(const short8v*)(gBl + k0 + 96);
            }
        }
        short8v afh0 = *(const short8v*)&Ah[p][(wy*32 +  0 + l15)*32 + lk];
        short8v afh1 = *(const short8v*)&Ah[p][(wy*32 + 16 + l15)*32 + lk];
        short8v afl0 = *(const short8v*)&Al[p][(wy*32 +  0 + l15)*32 + lk];
        short8v afl1 = *(const short8v*)&Al[p][(wy*32 + 16 + l15)*32 + lk];
        short8v bfh0 = *(const short8v*)&Bh[p][(wx*32 +  0 + l15)*32 + lk];
        short8v bfh1 = *(const short8v*)&Bh[p][(wx*32 + 16 + l15)*32 + lk];
        short8v bfl0 = *(const short8v*)&Bl[p][(wx*32 +  0 + l15)*32 + lk];
        short8v bfl1 = *(const short8v*)&Bl[p][(wx*32 + 16 + l15)*32 + lk];
        MFMA3(acc[0][0], afh0, afl0, bfh0, bfl0);
        MFMA3(acc[0][1], afh0, afl0, bfh1, bfl1);
        MFMA3(acc[1][0], afh1, afl1, bfh0, bfl0);
        MFMA3(acc[1][1], afh1, afl1, bfh1, bfl1);
        __syncthreads();
        p ^= 1;
    }

    int col0 = nbase + wx*32 + l15;
    if (isL){
        float bo0 = bo[col0], bo1 = bo[col0 + 16];
#pragma unroll
        for (int mf = 0; mf < 2; ++mf){
#pragma unroll
            for (int r = 0; r < 4; ++r){
                int row = m0 + wy*32 + mf*16 + rg*4 + r;
                float v0 = acc[mf][0][r] + bo0;
                float v1 = acc[mf][1][r] + bo1;
                float* crow = logits + (size_t)row * (NSTEP * (size_t)V_);
                crow[col0]      = v0;
                crow[col0 + 16] = v1;
                unsigned long long k0_ = ((unsigned long long)fkey(v0) << 32) | (unsigned)(4095 - col0);
                unsigned long long k1_ = ((unsigned long long)fkey(v1) << 32) | (unsigned)(4095 - (col0+16));
                unsigned long long best = k0_ > k1_ ? k0_ : k1_;
#pragma unroll
                for (int off = 1; off < 16; off <<= 1){
                    unsigned long long o = __shfl_xor(best, off);
                    if (o > best) best = o;
                }
                if (l15 == 0) atomicMax(&Pcur[row], best);
            }
        }
    } else {
#pragma unroll
        for (int mf = 0; mf < 2; ++mf)
#pragma unroll
            for (int r = 0; r < 4; ++r){
                int row = m0 + wy*32 + mf*16 + rg*4 + r;
                gh_out[(size_t)row*1536 + col0]      = acc[mf][0][r];
                gh_out[(size_t)row*1536 + col0 + 16] = acc[mf][1][r];
            }
    }
}

// ---------------- front3: eproj(128x128, XCD-swizzled, 32KB) U gictx U gh0 ----------------
__global__ __launch_bounds__(256) void front3(
    const u16* __restrict__ EmbHi, const u16* __restrict__ EmbLo,
    const u16* __restrict__ WihLHi, const u16* __restrict__ WihLLo,
    float* __restrict__ Eproj,
    const float* __restrict__ ctx, const float* __restrict__ WihR,
    const float* __restrict__ bih, float* __restrict__ gictx,
    const u16* __restrict__ Sh0, const u16* __restrict__ Sl0,
    const u16* __restrict__ WhhHi, const u16* __restrict__ WhhLo,
    float* __restrict__ gh0)
{
    __shared__ __align__(16) char smem[32768];
    int b = blockIdx.x, tid = threadIdx.x;
    if (b < 384){
        int work = (b & 7) * 48 + (b >> 3);   // 384 = 8 * 48, bijective
        int bm = work / 12, bn = work % 12;
        int n0 = bn * 128, m0 = bm * 128;
        int lane = tid & 63, wid = tid >> 6;
        int wy = wid & 1, wx = wid >> 1;
        int l15 = lane & 15, rg = lane >> 4, lk = rg * 8;
        u16* Ah = (u16*)smem;
        u16* Al = (u16*)(smem + 8192);
        u16* Bh = (u16*)(smem + 16384);
        u16* Bl = (u16*)(smem + 24576);
        const u16* gA[2][2]; const u16* gB[2][2];
#pragma unroll
        for (int j = 0; j < 2; ++j){
            int s = tid + j*256;
            int row = s >> 2, k8 = (s & 3)*8;
            gA[0][j] = EmbHi + (size_t)(m0+row)*1024 + k8;
            gA[1][j] = EmbLo + (size_t)(m0+row)*1024 + k8;
            gB[0][j] = WihLHi + (size_t)(n0+row)*1024 + k8;
            gB[1][j] = WihLLo + (size_t)(n0+row)*1024 + k8;
        }
        short8v rA[2][2], rB[2][2];
#pragma unroll
        for (int h = 0; h < 2; ++h)
#pragma unroll
            for (int j = 0; j < 2; ++j){
                rA[h][j] = *(const short8v*)gA[h][j];
                rB[h][j] = *(const short8v*)gB[h][j];
            }
        f32x4 acc[4][4] = {};
        for (int k0 = 0; k0 < 1024; k0 += 32){
            __syncthreads();
#pragma unroll
            for (int j = 0; j < 2; ++j){
                int s8 = (tid + j*256)*8;
                *(short8v*)&Ah[s8] = rA[0][j];
                *(short8v*)&Al[s8] = rA[1][j];
                *(short8v*)&Bh[s8] = rB[0][j];
                *(short8v*)&Bl[s8] = rB[1][j];
            }
            __syncthreads();
            if (k0 + 32 < 1024){
#pragma unroll
                for (int h = 0; h < 2; ++h)
#pragma unroll
                    for (int j = 0; j < 2; ++j){
                        rA[h][j] = *(const short8v*)(gA[h][j] + k0 + 32);
                        rB[h][j] = *(const short8v*)(gB[h][j] + k0 + 32);
                    }
            }
            short8v afh[4], afl[4];
#pragma unroll
            for (int mf = 0; mf < 4; ++mf){
                afh[mf] = *(const short8v*)&Ah[(wy*64 + mf*16 + l15)*32 + lk];
                afl[mf] = *(const short8v*)&Al[(wy*64 + mf*16 + l15)*32 + lk];
            }
#pragma unroll
            for (int nf = 0; nf < 4; ++nf){
                short8v bfh = *(const short8v*)&Bh[(wx*64 + nf*16 + l15)*32 + lk];
                short8v bfl = *(const short8v*)&Bl[(wx*64 + nf*16 + l15)*32 + lk];
#pragma unroll
                for (int mf = 0; mf < 4; ++mf)
                    MFMA3(acc[mf][nf], afh[mf], afl[mf], bfh, bfl);
            }
        }
        int col0 = n0 + wx*64 + l15;
#pragma unroll
        for (int mf = 0; mf < 4; ++mf)
#pragma unroll
            for (int r = 0; r < 4; ++r){
                int row = m0 + wy*64 + mf*16 + rg*4 + r;
#pragma unroll
                for (int nf = 0; nf < 4; ++nf)
                    Eproj[(size_t)row*1536 + col0 + nf*16] = acc[mf][nf][r];
            }
    } else if (b < 576){
        int lb = b - 384;
        int m0 = (lb & 7) * 32, n0 = (lb >> 3) * 64;
        float (*As)[36] = (float(*)[36])smem;
        float (*Bs)[68] = (float(*)[68])(smem + 2304);
        int lk = tid & 15, lr = tid >> 4;
        int tx = tid & 15, ty = tid >> 4;
        float c[2][4] = {};
        for (int k0 = 0; k0 < 512; k0 += 16){
#pragma unroll
            for (int i = 0; i < 2; ++i)
                As[lk][lr*2 + i] = ctx[(size_t)(m0 + lr*2 + i)*512 + k0 + lk];
#pragma unroll
            for (int i = 0; i < 4; ++i)
                Bs[lk][lr*4 + i] = WihR[(size_t)(n0 + lr*4 + i)*1536 + k0 + lk];
            __syncthreads();
#pragma unroll
            for (int k = 0; k < 16; ++k){
                float b4[4];
                *(float4*)b4 = *(const float4*)&Bs[k][tx*4];
#pragma unroll
                for (int i = 0; i < 2; ++i){
                    float a = As[k][ty*2 + i];
#pragma unroll
                    for (int j = 0; j < 4; ++j) c[i][j] += a * b4[j];
                }
            }
            __syncthreads();
        }
#pragma unroll
        for (int j = 0; j < 4; ++j){
            float bb = bih[n0 + tx*4 + j];
#pragma unroll
            for (int i = 0; i < 2; ++i)
                gictx[(size_t)(m0 + ty*2 + i)*1536 + n0 + tx*4 + j] = c[i][j] + bb;
        }
    } else {
        int lb = b - 576;
        step_mm_body(smem, (lb & 3)*64, lb >> 2, 0,
                     Sh0, Sl0, nullptr, nullptr, WhhHi, WhhLo,
                     nullptr, nullptr, nullptr, gh0);
    }
}

// ---------------- per-step kernels ----------------
__global__ __launch_bounds__(128) void gru_pointwise(
    const float* __restrict__ gh, const float* __restrict__ Eproj,
    const float* __restrict__ gictx, const float* __restrict__ bhh,
    const float* __restrict__ hprev, float* __restrict__ hnext,
    u16* __restrict__ Sh, u16* __restrict__ Sl,
    const unsigned long long* __restrict__ Pprev,
    float* __restrict__ preds, int t)
{
    int tid = threadIdx.x;
    int row = blockIdx.x;
    int jj = tid * 4;
    int w = 1;
    if (t > 0){
        w = 4095 - (int)(Pprev[row] & 0xFFFFFFFFull);
        if (w < 0) w = 0; if (w > 4095) w = 4095;
        if (tid == 0) preds[row*NSTEP + (t-1)] = (float)w;
    }
    const float* gr = gh + (size_t)row * 1536;
    const float* ep = Eproj + (size_t)w * 1536;
    const float* gc = gictx + (size_t)row * 1536;
    float4 g0 = *(const float4*)&gr[jj];
    float4 g1 = *(const float4*)&gr[512 + jj];
    float4 g2 = *(const float4*)&gr[1024 + jj];
    float4 e0 = *(const float4*)&ep[jj];
    float4 e1 = *(const float4*)&ep[512 + jj];
    float4 e2 = *(const float4*)&ep[1024 + jj];
    float4 c0 = *(const float4*)&gc[jj];
    float4 c1 = *(const float4*)&gc[512 + jj];
    float4 c2 = *(const float4*)&gc[1024 + jj];
    float4 b0 = *(const float4*)&bhh[jj];
    float4 b1 = *(const float4*)&bhh[512 + jj];
    float4 b2 = *(const float4*)&bhh[1024 + jj];
    float4 ho = *(const float4*)&hprev[(size_t)row*512 + jj];
    const float* G0 = (const float*)&g0; const float* G1 = (const float*)&g1;
    const float* G2 = (const float*)&g2;
    const float* E0 = (const float*)&e0; const float* E1 = (const float*)&e1;
    const float* E2 = (const float*)&e2;
    const float* C0 = (const float*)&c0; const float* C1 = (const float*)&c1;
    const float* C2 = (const float*)&c2;
    const float* B0 = (const float*)&b0; const float* B1 = (const float*)&b1;
    const float* B2 = (const float*)&b2;
    const float* HO = (const float*)&ho;
    float4 res;
    float* R = (float*)&res;
#pragma unroll
    for (int i = 0; i < 4; ++i){
        float gir = E0[i] + C0[i] + G0[i] + B0[i];
        float giz = E1[i] + C1[i] + G1[i] + B1[i];
        float gin = E2[i] + C2[i];
        float rr = 1.f / (1.f + expf(-gir));
        float zz = 1.f / (1.f + expf(-giz));
        float nn = tanhf(gin + rr * (G2[i] + B2[i]));
        R[i] = (1.f - zz)*nn + zz*HO[i];
    }
    size_t o = (size_t)row*512 + jj;
    *(float4*)&hnext[o] = res;
    ushort4v h4, l4; split_f4(res, h4, l4);
    *(ushort4v*)&Sh[o] = h4;
    *(ushort4v*)&Sl[o] = l4;
}

// 32-row x 64-col tiles, 704 blocks (2.75/CU), XCD-swizzled.
__global__ __launch_bounds__(256) void step_mm(
    const u16* __restrict__ Ahg, const u16* __restrict__ Alg,
    const u16* __restrict__ WoHi, const u16* __restrict__ WoLo,
    const u16* __restrict__ WhhHi, const u16* __restrict__ WhhLo,
    const float* __restrict__ bo,
    float* __restrict__ logits, unsigned long long* __restrict__ Pcur,
    float* __restrict__ gh_out, int n_logits)
{
    __shared__ __align__(16) char smem[24576];
    u16 (*Ah)[1024] = (u16(*)[1024])(smem);
    u16 (*Al)[1024] = (u16(*)[1024])(smem + 4096);
    u16 (*Bh)[2048] = (u16(*)[2048])(smem + 8192);
    u16 (*Bl)[2048] = (u16(*)[2048])(smem + 16384);
    int bid = blockIdx.x;
    int work = (bid & 7) * 88 + (bid >> 3);
    int m0 = (work & 7) * 32;
    int nt = work >> 3;
    bool isL = nt < n_logits;
    int nbase = (isL ? nt : nt - n_logits) * 64;
    const u16* Bhg = isL ? WoHi : WhhHi;
    const u16* Blg = isL ? WoLo : WhhLo;
    int tid = threadIdx.x, lane = tid & 63, wid = tid >> 6;
    int wy = wid & 1, wx = wid >> 1;
    int l15 = lane & 15, rg = lane >> 4, lk = rg * 8;

    int ahalf = tid >> 7, ai = tid & 127;
    int ar = ai >> 2, ak8 = (ai & 3) * 8;
    const u16* gA = (ahalf ? Alg : Ahg) + (size_t)(m0 + ar)*512 + ak8;
    u16 (*Adst)[1024] = ahalf ? Al : Ah;
    int br = tid >> 2, bk8 = (tid & 3) * 8;
    const u16* gBh = Bhg + (size_t)(nbase + br)*512 + bk8;
    const u16* gBl = Blg + (size_t)(nbase + br)*512 + bk8;

    *(short8v*)&Adst[0][ai*8] = *(const short8v*)gA;
    *(short8v*)&Bh[0][tid*8] = *(const short8v*)gBh;
    *(short8v*)&Bl[0][tid*8] = *(const short8v*)gBl;
    short8v a1 = *(const short8v*)(gA + 32),  a2 = *(const short8v*)(gA + 64);
    short8v h1 = *(const short8v*)(gBh + 32), h2 = *(const short8v*)(gBh + 64);
    short8v l1 = *(const short8v*)(gBl + 32), l2 = *(const short8v*)(gBl + 64);
    __syncthreads();

    f32x4 acc[2] = {};
    int p = 0;
    for (int k0 = 0; k0 < 512; k0 += 32){
        if (k0 + 32 < 512){
            *(short8v*)&Adst[p^1][ai*8] = a1;
            *(short8v*)&Bh[p^1][tid*8] = h1;
            *(short8v*)&Bl[p^1][tid*8] = l1;
            a1 = a2; h1 = h2; l1 = l2;
            if (k0 + 96 < 512){
                a2 = *(const short8v*)(gA + k0 + 96);
                h2 = *(const short8v*)(gBh + k0 + 96);
                l2 = *(const short8v*)(gBl + k0 + 96);
            }
        }
        short8v afh = *(const short8v*)&Ah[p][(wy*16 + l15)*32 + lk];
        short8v afl = *(const short8v*)&Al[p][(wy*16 + l15)*32 + lk];
        short8v bfh0 = *(const short8v*)&Bh[p][(wx*32 +  0 + l15)*32 + lk];
        short8v bfh1 = *(const short8v*)&Bh[p][(wx*32 + 16 + l15)*32 + lk];
        short8v bfl0 = *(const short8v*)&Bl[p][(wx*32 +  0 + l15)*32 + lk];
        short8v bfl1 = *(const short8v*)&Bl[p][(wx*32 + 16 + l15)*32 + lk];
        MFMA3(acc[0], afh, afl, bfh0, bfl0);
        MFMA3(acc[1], afh, afl, bfh1, bfl1);
        __syncthreads();
        p ^= 1;
    }

    int col0 = nbase + wx*32 + l15;
    if (isL){
        float bo0 = bo[col0], bo1 = bo[col0 + 16];
#pragma unroll
        for (int r = 0; r < 4; ++r){
            int row = m0 + wy*16 + rg*4 + r;
            float v0 = acc[0][r] + bo0;
            float v1 = acc[1][r] + bo1;
            float* crow = logits + (size_t)row * (NSTEP * (size_t)V_);
            crow[col0]      = v0;
            crow[col0 + 16] = v1;
            unsigned long long k0_ = ((unsigned long long)fkey(v0) << 32) | (unsigned)(4095 - col0);
            unsigned long long k1_ = ((unsigned long long)fkey(v1) << 32) | (unsigned)(4095 - (col0+16));
            unsigned long long best = k0_ > k1_ ? k0_ : k1_;
#pragma unroll
            for (int off = 1; off < 16; off <<= 1){
                unsigned long long o = __shfl_xor(best, off);
                if (o > best) best = o;
            }
            if (l15 == 0) atomicMax(&Pcur[row], best);
        }
    } else {
#pragma unroll
        for (int r = 0; r < 4; ++r){
            int row = m0 + wy*16 + rg*4 + r;
            gh_out[(size_t)row*1536 + col0]      = acc[0][r];
            gh_out[(size_t)row*1536 + col0 + 16] = acc[1][r];
        }
    }
}

__global__ __launch_bounds__(256) void final_pred(const unsigned long long* __restrict__ P,
                                                  float* __restrict__ preds){
    int b = threadIdx.x;
    int w = 4095 - (int)(P[b] & 0xFFFFFFFFull);
    if (w < 0) w = 0; if (w > 4095) w = 4095;
    preds[b*NSTEP + (NSTEP-1)] = (float)w;
}

extern "C" void kernel_launch(void* const* d_in, const int* in_sizes, int n_in,
                              void* d_out, int out_size, void* d_ws, size_t ws_size,
                              hipStream_t stream){
    const float* elhs = (const float*)d_in[0];
    const float* enc  = (const float*)d_in[1];
    const float* emb  = (const float*)d_in[3];
    const float* W1   = (const float*)d_in[4];
    const float* W2   = (const float*)d_in[6];
    const float* W3   = (const float*)d_in[8];
    const float* W4   = (const float*)d_in[10];
    const float* Ww   = (const float*)d_in[12];
    const float* Wih  = (const float*)d_in[13];
    const float* bih  = (const float*)d_in[14];
    const float* Whh  = (const float*)d_in[15];
    const float* bhh  = (const float*)d_in[16];
    const float* Wo   = (const float*)d_in[17];
    const float* bo   = (const float*)d_in[18];

    float* out = (float*)d_out;
    float* preds = out + (size_t)B_ * NSTEP * V_;

    float* ws = (float*)d_ws;
    float* Eproj  = ws;  ws += (size_t)V_ * 1536;
    float* gictx  = ws;  ws += (size_t)B_ * 1536;
    float* ctx    = ws;  ws += B_ * H_;
    float* t1     = ws;  ws += 512;
    float* t2     = ws;  ws += 512;
    float* weff   = ws;  ws += 512;
    float* Hf     = ws;  ws += 2 * B_ * H_;
    float* ghbuf  = ws;  ws += B_ * 1536;
    u16* WoT_hi = (u16*)ws;  ws += (size_t)V_ * 512 / 2;
    u16* WoT_lo = (u16*)ws;  ws += (size_t)V_ * 512 / 2;
    u16* WhhHi  = (u16*)ws;  ws += 1536 * 512 / 2;
    u16* WhhLo  = (u16*)ws;  ws += 1536 * 512 / 2;
    u16* Sh     = (u16*)ws;  ws += B_ * H_ / 2;
    u16* Sl     = (u16*)ws;  ws += B_ * H_ / 2;
    unsigned long long* P = (unsigned long long*)ws;   // 27*256 u64

    // big one-time splits parked in d_out head (consumed by front3 before logits writes)
    u16* EmbHi  = (u16*)d_out;
    u16* EmbLo  = EmbHi + (size_t)V_*1024;
    u16* WihLHi = EmbLo + (size_t)V_*1024;
    u16* WihLLo = WihLHi + (size_t)1536*1024;

    prep_all<<<7182, 256, 0, stream>>>(Whh, Wo, emb, Wih, elhs, W4, Ww,
                                       WhhHi, WhhLo, WoT_hi, WoT_lo,
                                       EmbHi, EmbLo, WihLHi, WihLLo,
                                       Sh, Sl, t1, (unsigned*)P, NSTEP*256*2);
    matvec512<<<512, 64, 0, stream>>>(W3, t1, t2);
    matvec512<<<512, 64, 0, stream>>>(W2, t2, t1);
    matvec512<<<512, 64, 0, stream>>>(W1, t1, weff);
    attn_ctx<<<B_, 512, 0, stream>>>(enc, weff, ctx);
    front3<<<672, 256, 0, stream>>>(EmbHi, EmbLo, WihLHi, WihLLo, Eproj,
                                    ctx, Wih + 1024, bih, gictx,
                                    Sh, Sl, WhhHi, WhhLo, ghbuf);

    for (int t = 0; t < NSTEP; ++t){
        const float* hr = (t == 0) ? elhs : (Hf + (size_t)((t-1) & 1) * (B_*H_));
        float*       hw = Hf + (size_t)(t & 1) * (B_*H_);
        const unsigned long long* Pprev = P + (size_t)(t > 0 ? t-1 : 0) * 256;
        gru_pointwise<<<256, 128, 0, stream>>>(ghbuf, Eproj, gictx, bhh, hr, hw,
                                               Sh, Sl, Pprev, preds, t);
        step_mm<<<704, 256, 0, stream>>>(Sh, Sl, WoT_hi, WoT_lo, WhhHi, WhhLo, bo,
                                         out + (size_t)t * V_, P + (size_t)t*256, ghbuf, 64);
    }
    final_pred<<<1, 256, 0, stream>>>(P + (size_t)(NSTEP-1)*256, preds);
}